// Round 9
// baseline (346.333 us; speedup 1.0000x reference)
//
#include <hip/hip_runtime.h>

// Problem constants (setup_inputs: B=64, N=4096, C=64, Cout=128, H=W=64)
#define BB 64
#define NN 4096
#define CCH 64
#define CO 128
#define HH 64
#define WW 64
#define H2 32
#define W2 32
#define EPSF 1e-6f
#define BNEPS 1e-5f

typedef unsigned short ushort_t;
using bf8  = __attribute__((ext_vector_type(8))) short;   // 8 bf16 (4 VGPRs)
using f32x4 = __attribute__((ext_vector_type(4))) float;  // MFMA accumulator

__device__ inline ushort_t f2bf(float f) {
  unsigned u = __float_as_uint(f);
  unsigned r = (u + 0x7fffu + ((u >> 16) & 1u)) >> 16;  // RNE
  return (ushort_t)r;
}
__device__ inline float bflo(unsigned u) { return __uint_as_float(u << 16); }
__device__ inline float bfhi(unsigned u) { return __uint_as_float(u & 0xffff0000u); }

__device__ inline void gload_lds16(const void* src, void* ldsdst) {
  __builtin_amdgcn_global_load_lds((const __attribute__((address_space(1))) void*)src,
                                   (__attribute__((address_space(3))) void*)ldsdst, 16, 0, 0);
}

__device__ inline void cells_from_loc(float lx, float ly, int& c64, int& c32) {
  lx = fminf(fmaxf(lx, -1.f), 1.f) * 0.5f + 0.5f;
  ly = fminf(fmaxf(ly, -1.f), 1.f) * 0.5f + 0.5f;
  int cx = (int)fminf(fmaxf(rintf(lx * (WW - 1)), 0.f), (float)(WW - 1));
  int cy = (int)fminf(fmaxf(rintf(ly * (HH - 1)), 0.f), (float)(HH - 1));
  c64 = cx + cy * WW;
  int cx2 = (int)fminf(fmaxf(rintf(lx * (W2 - 1)), 0.f), (float)(W2 - 1));
  int cy2 = (int)fminf(fmaxf(rintf(ly * (H2 - 1)), 0.f), (float)(H2 - 1));
  c32 = cx2 + cy2 * W2;
}

// ---------- K0: fast zero of the metadata region ----------
__global__ __launch_bounds__(256) void k_zero(uint4* __restrict__ p) {
  p[blockIdx.x * 256 + threadIdx.x] = make_uint4(0u, 0u, 0u, 0u);  // 849*256*16 B
}

// ---------- K1: cells + idx_agg_down output + counts + NRM; blocks >=1024: bf16 weights ----------
__global__ __launch_bounds__(256) void k_prep(const float* __restrict__ loc, const int* __restrict__ idxagg,
                                              const float* __restrict__ aw,
                                              float* __restrict__ idx_out,
                                              unsigned* __restrict__ pck64, unsigned* __restrict__ pck32,
                                              unsigned* __restrict__ pckT, float* __restrict__ nrm,
                                              const float* __restrict__ convw, const float* __restrict__ skipw,
                                              ushort_t* __restrict__ wT, ushort_t* __restrict__ swT) {
  int blk = blockIdx.x;  // 1344
  if (blk >= 1024) {     // fused weight prep (320 blocks' worth)
    int e = (blk - 1024) * 256 + threadIdx.x;  // < 81920
    if (e < 9 * CCH * CO) {
      int co = e & 127, k = e >> 7;
      wT[co * 576 + k] = f2bf(convw[k * CO + co]);
    } else {
      int e2 = e - 9 * CCH * CO;
      int co = e2 & 127, k = e2 >> 7;
      swT[co * 64 + k] = f2bf(skipw[k * CO + co]);
    }
    return;
  }
  int i = blk * 256 + threadIdx.x;  // exactly B*N = 262144
  int b = i >> 12;
  int c64, c2;
  cells_from_loc(loc[2 * i], loc[2 * i + 1], c64, c2);
  idx_out[i] = (float)c2;
  atomicAdd(&pck64[(b << 12) + c64], 1u);
  atomicAdd(&pck32[(b << 10) + c2], 1u);
  atomicAdd(&pckT[(b << 12) + idxagg[i]], 1u);
  unsafeAtomicAdd(&nrm[(b << 12) + idxagg[i]], aw[i]);
}

// ---------- scan helper: in-place exclusive scan; buf[i]: count -> (off<<16)|off ----------
__device__ void block_exscan_pack(unsigned* __restrict__ buf, int L) {
  __shared__ int partial[256];
  int tid = threadIdx.x;
  int per = L >> 8;
  int base = tid * per;
  int s = 0;
  for (int i = 0; i < per; i++) s += (int)buf[base + i];
  __syncthreads();
  partial[tid] = s;
  __syncthreads();
  for (int d = 1; d < 256; d <<= 1) {
    int v = (tid >= d) ? partial[tid - d] : 0;
    __syncthreads();
    partial[tid] += v;
    __syncthreads();
  }
  int run = (tid == 0) ? 0 : partial[tid - 1];
  for (int i = 0; i < per; i++) {
    int n = (int)buf[base + i];
    buf[base + i] = ((unsigned)run << 16) | (unsigned)run;
    run += n;
  }
}

// ---------- K3: per-batch prefix scans; one block per (batch, sort-kind) ----------
__global__ __launch_bounds__(256) void k_scan(unsigned* __restrict__ pck64, unsigned* __restrict__ pckT,
                                              unsigned* __restrict__ pck32) {
  int b = blockIdx.x / 3, kind = blockIdx.x - 3 * (blockIdx.x / 3);  // 192 blocks
  if (kind == 0)      block_exscan_pack(pck64 + ((size_t)b << 12), 4096);
  else if (kind == 1) block_exscan_pack(pckT + ((size_t)b << 12), 4096);
  else                block_exscan_pack(pck32 + ((size_t)b << 10), 1024);
}

// ---------- K4: fill sorted packed lists; blocks >=1024: zero map borders ----------
__global__ __launch_bounds__(256) void k_fill(const float* __restrict__ loc, const int* __restrict__ idxagg,
                                              const float* __restrict__ aw,
                                              unsigned* __restrict__ pck64, unsigned* __restrict__ pckT,
                                              unsigned* __restrict__ pck32,
                                              ushort_t* __restrict__ list64, unsigned* __restrict__ listT,
                                              unsigned* __restrict__ list32, ushort_t* __restrict__ xmb) {
  int blk = blockIdx.x;  // 2064
  if (blk >= 1024) {     // fused border zero (1040 blocks' worth)
    int t = (blk - 1024) * 256 + threadIdx.x;  // exactly 64*260*16 = 266240
    int q = t & 15;
    int cell = (t >> 4) % 260;
    int b = t / (260 * 16);
    int r, c;
    if (cell < 66)       { r = 0;  c = cell; }
    else if (cell < 132) { r = 65; c = cell - 66; }
    else if (cell < 196) { r = cell - 132 + 1; c = 0; }
    else                 { r = cell - 196 + 1; c = 65; }
    *(uint2*)&xmb[(((size_t)(b * 66 + r)) * 66 + c) * 64 + q * 4] = make_uint2(0u, 0u);
    return;
  }
  int i = blk * 256 + threadIdx.x;  // B*N
  int b = i >> 12, p = i & 4095;
  int c64, c2;
  cells_from_loc(loc[2 * i], loc[2 * i + 1], c64, c2);
  int idx = idxagg[i];
  unsigned pos = atomicAdd(&pck64[(b << 12) + c64], 1u) & 0xffffu;
  list64[(b << 12) + pos] = (ushort_t)idx;                       // token index
  pos = atomicAdd(&pckT[(b << 12) + idx], 1u) & 0xffffu;
  listT[(b << 12) + pos] = ((unsigned)c2 << 16) | (unsigned)f2bf(aw[i]);  // {cell, aw-bf16}
  pos = atomicAdd(&pck32[(b << 10) + c2], 1u) & 0xffffu;
  list32[(b << 12) + pos] = ((unsigned)idx << 16) | (unsigned)p;          // {token idx, point id}
}

// ---------- K5: token2map GATHER; 8 cells/wave; register-resident records via shfl ----------
// (uniform-index, full-exec shfl only — the validated pattern)
__global__ __launch_bounds__(256) void k_t2m(const float* __restrict__ x,
                                             const unsigned* __restrict__ pck64,
                                             const ushort_t* __restrict__ list64, ushort_t* __restrict__ xmb) {
  int blk = blockIdx.x;                       // 8192
  int xcd = blk & 7, lblk = blk >> 3;         // XCD k owns batches [k*8, k*8+8)
  int wave = threadIdx.x >> 6, lane = threadIdx.x & 63;
  int cbase = xcd * 32768 + lblk * 32 + wave * 8;   // 8 consecutive cells per wave (one batch)
  int b = cbase >> 12;
  // 8 cell descriptors via 2 wave-uniform 16B loads
  unsigned pcks[8];
  *(uint4*)&pcks[0] = *(const uint4*)&pck64[cbase];
  *(uint4*)&pcks[4] = *(const uint4*)&pck64[cbase + 4];
  int o0 = (int)(pcks[0] >> 16);
  int total = (int)(pcks[7] & 0xffffu) - o0;  // low16 post-fill = end cursor
  const ushort_t* lp0 = list64 + ((size_t)b << 12) + o0;
  int myrec = (lane < total) ? (int)lp0[lane] : 0;  // ALL 8 cells' records in one coalesced load
  const float* xb = x + ((size_t)b << 18);
#pragma unroll 1
  for (int k = 0; k < 8; k++) {
    int off = (int)(pcks[k] >> 16) - o0;
    int n = (int)(pcks[k] & 0xffffu) - (int)(pcks[k] >> 16);
    float s0 = 0.f, s1 = 0.f, s2 = 0.f, s3 = 0.f;
    int i = 0;
    for (; i + 4 <= n; i += 4) {
      int j = off + i;  // uniform
      int i0 = (j     < 64) ? __shfl(myrec, j,     64) : (int)lp0[j];
      int i1 = (j + 1 < 64) ? __shfl(myrec, j + 1, 64) : (int)lp0[j + 1];
      int i2 = (j + 2 < 64) ? __shfl(myrec, j + 2, 64) : (int)lp0[j + 2];
      int i3 = (j + 3 < 64) ? __shfl(myrec, j + 3, 64) : (int)lp0[j + 3];
      s0 += xb[(size_t)i0 * 64 + lane];
      s1 += xb[(size_t)i1 * 64 + lane];
      s2 += xb[(size_t)i2 * 64 + lane];
      s3 += xb[(size_t)i3 * 64 + lane];
    }
    for (; i < n; i++) {
      int j = off + i;
      int i0 = (j < 64) ? __shfl(myrec, j, 64) : (int)lp0[j];
      s0 += xb[(size_t)i0 * 64 + lane];
    }
    float avg = (s0 + s1 + s2 + s3) / ((float)n + EPSF);
    int cell = (cbase + k) & 4095;
    int r = cell >> 6, cc = cell & 63;
    xmb[(((size_t)(b * 66 + r + 1)) * 66 + cc + 1) * 64 + lane] = f2bf(avg);
  }
}

// ---------- K6: conv 3x3 stride2 pad1 implicit GEMM; bf16 Y out (verified) ----------
__global__ __launch_bounds__(256) void k_conv(const ushort_t* __restrict__ xmb, const ushort_t* __restrict__ wT,
                                              const float* __restrict__ cb, ushort_t* __restrict__ y) {
  __shared__ ushort_t A[2][4096];
  const int tid = threadIdx.x;
  const int wave = tid >> 6, lane = tid & 63;
  const int m0 = blockIdx.x * 128;

  f32x4 acc[2][8];
  {
    float bv[8];
#pragma unroll
    for (int nt = 0; nt < 8; nt++) bv[nt] = cb[nt * 16 + (lane & 15)];
#pragma unroll
    for (int mt = 0; mt < 2; mt++)
#pragma unroll
      for (int nt = 0; nt < 8; nt++) {
        f32x4 a; a[0] = bv[nt]; a[1] = bv[nt]; a[2] = bv[nt]; a[3] = bv[nt];
        acc[mt][nt] = a;
      }
  }

  const int srcslot = (((lane & 3) ^ ((lane >> 3) & 3))) * 8;
  int sb[2], soy[2], sox[2];
#pragma unroll
  for (int q = 0; q < 2; q++) {
    int r = wave * 32 + q * 16 + (lane >> 2);
    int s = m0 + r;
    sb[q] = s >> 10; soy[q] = (s >> 5) & 31; sox[q] = s & 31;
  }

  auto stage = [&](int ks, int buf) {
    int kp = ks >> 1, ci0 = (ks & 1) * 32;
    int ky = kp / 3, kx = kp - ky * 3;
#pragma unroll
    for (int q = 0; q < 2; q++) {
      int iy = 2 * soy[q] + ky, ix = 2 * sox[q] + kx;
      const ushort_t* src = xmb + (((size_t)sb[q] * 66 + iy) * 66 + ix) * 64 + ci0 + srcslot;
      gload_lds16(src, &A[buf][(wave * 32 + q * 16) * 32]);
    }
  };

  stage(0, 0);
  const int rdslotx = (lane >> 1) & 3;
  for (int ks = 0; ks < 18; ks++) {
    int buf = ks & 1;
    __syncthreads();
    if (ks < 17) stage(ks + 1, buf ^ 1);
    bf8 a[2];
#pragma unroll
    for (int mt = 0; mt < 2; mt++) {
      int r = wave * 32 + mt * 16 + (lane & 15);
      int slot = (lane >> 4) ^ rdslotx;
      a[mt] = *(const bf8*)&A[buf][r * 32 + slot * 8];
    }
    int k0 = ks * 32 + (lane >> 4) * 8;
#pragma unroll
    for (int nt = 0; nt < 8; nt++) {
      int co = nt * 16 + (lane & 15);
      bf8 bbf = *(const bf8*)&wT[co * 576 + k0];
      acc[0][nt] = __builtin_amdgcn_mfma_f32_16x16x32_bf16(a[0], bbf, acc[0][nt], 0, 0, 0);
      acc[1][nt] = __builtin_amdgcn_mfma_f32_16x16x32_bf16(a[1], bbf, acc[1][nt], 0, 0, 0);
    }
  }
#pragma unroll
  for (int mt = 0; mt < 2; mt++)
#pragma unroll
    for (int nt = 0; nt < 8; nt++) {
      int co = nt * 16 + (lane & 15);
#pragma unroll
      for (int j = 0; j < 4; j++) {
        int srow = m0 + wave * 32 + mt * 16 + (lane >> 4) * 4 + j;
        y[(size_t)srow * 128 + co] = f2bf(acc[mt][nt][j]);
      }
    }
}

// ---------- K7: FUSED xt = gather_m2t(y)/nrm + x@skip_w + BN partials; bf16 XT out ----------
__global__ __launch_bounds__(256) void k_xt(const float* __restrict__ x, const ushort_t* __restrict__ swT,
                                            const ushort_t* __restrict__ y,
                                            const unsigned* __restrict__ listT, const unsigned* __restrict__ pckT,
                                            const float* __restrict__ nrm,
                                            ushort_t* __restrict__ XTB, float* __restrict__ BNP) {
  __shared__ float xg[64 * 128];   // 32 KB: x staging (first 16 KB) -> gather accum -> bf16 out (alias)
  __shared__ float nrminv[64];
  __shared__ float bnred[256];
  const int tid = threadIdx.x, wave = tid >> 6, lane = tid & 63;
  int blk = blockIdx.x;                       // 4096
  int sblk = (blk & 7) * 512 + (blk >> 3);    // XCD swizzle (8 batches per XCD)
  const int t0 = sblk * 64;
  const int b = t0 >> 12, lt0 = t0 & 4095;

  // ---- issue-early: token offsets (independent of everything below)
  int myoff = 0;
  {
    int gtok = lt0 + wave * 16 + lane;
    if (lane <= 16) myoff = (gtok >= NN) ? NN : (int)(pckT[(b << 12) + gtok] >> 16);
  }

  // ---- stage x tile (64x64 f32 = 16 KB), 16 chunks of 4 rows, swizzled 16B slots
#pragma unroll
  for (int q = 0; q < 4; q++) {
    int ch = wave * 4 + q;
    int r = ch * 4 + (lane >> 4);
    int sp = lane & 15;
    const float* src = x + ((size_t)(t0 + r)) * 64 + ((sp ^ (r & 7)) << 2);
    gload_lds16(src, (char*)xg + ch * 1024);
  }
  if (tid < 64) nrminv[tid] = 1.f / (nrm[(b << 12) + lt0 + tid] + EPSF);
  bnred[tid] = 0.f;
  __syncthreads();

  // ---- A fragments (f32 -> bf16)
  bf8 afr[2];
  {
    int r = wave * 16 + (lane & 15);
#pragma unroll
    for (int ks = 0; ks < 2; ks++) {
      int cs = ks * 4 + (lane >> 4);
      const float4 f0 = *(const float4*)&xg[r * 64 + (((2 * cs) ^ (r & 7)) << 2)];
      const float4 f1 = *(const float4*)&xg[r * 64 + (((2 * cs + 1) ^ (r & 7)) << 2)];
      bf8 v;
      v[0] = (short)f2bf(f0.x); v[1] = (short)f2bf(f0.y);
      v[2] = (short)f2bf(f0.z); v[3] = (short)f2bf(f0.w);
      v[4] = (short)f2bf(f1.x); v[5] = (short)f2bf(f1.y);
      v[6] = (short)f2bf(f1.z); v[7] = (short)f2bf(f1.w);
      afr[ks] = v;
    }
  }

  // ---- skip GEMM: wave computes rows [wave*16, wave*16+16) x 128 cols
  f32x4 acc[8];
#pragma unroll
  for (int nt = 0; nt < 8; nt++) { f32x4 z; z[0] = 0; z[1] = 0; z[2] = 0; z[3] = 0; acc[nt] = z; }
#pragma unroll
  for (int ks = 0; ks < 2; ks++)
#pragma unroll
    for (int nt = 0; nt < 8; nt++) {
      int co = nt * 16 + (lane & 15);
      bf8 bbf = *(const bf8*)&swT[co * 64 + ks * 32 + (lane >> 4) * 8];
      acc[nt] = __builtin_amdgcn_mfma_f32_16x16x32_bf16(afr[ks], bbf, acc[nt], 0, 0, 0);
    }

  __syncthreads();  // all waves' fragment reads done; xg reusable as gather accum

  // ---- prefetch chunk-0 records, then zero own gather rows
  int pbeg = __shfl(myoff, 0, 64), pend = __shfl(myoff, 16, 64);
  const unsigned* ltb = listT + ((size_t)b << 12);
  unsigned rec = (pbeg + lane < pend) ? ltb[pbeg + lane] : 0u;
#pragma unroll
  for (int rr = 0; rr < 16; rr++) {
    *(float2*)&xg[(wave * 16 + rr) * 128 + ((2 * lane) ^ ((rr & 7) << 4))] = make_float2(0.f, 0.f);
  }

  // ---- m2t gather: double-buffered record chunks; 4-deep y-row pipeline
  {
    const ushort_t* yb = y + ((size_t)b << 17);  // b*1024*128 ushorts
    for (int chunk = pbeg; chunk < pend; chunk += 64) {
      int pid = chunk + lane;
      unsigned currec = rec;
      if (chunk + 64 < pend) rec = (pid + 64 < pend) ? ltb[pid + 64] : 0u;  // prefetch next
      int rr = 0;
#pragma unroll
      for (int j = 1; j <= 16; j++) rr += (pid >= __shfl(myoff, j, 64)) ? 1 : 0;
      int nrec = min(64, pend - chunk);
      int i = 0;
      for (; i + 4 <= nrec; i += 4) {
        unsigned yu[4]; float vv[4]; int rw[4];
#pragma unroll
        for (int u = 0; u < 4; u++) {
          unsigned rb = (unsigned)__shfl((int)currec, i + u, 64);
          vv[u] = __uint_as_float(rb << 16);
          rw[u] = __shfl(rr, i + u, 64);
          yu[u] = *(const unsigned*)&yb[(size_t)(rb >> 16) * 128 + lane * 2];
        }
#pragma unroll
        for (int u = 0; u < 4; u++) {
          float2* p = (float2*)&xg[(wave * 16 + rw[u]) * 128 + ((2 * lane) ^ ((rw[u] & 7) << 4))];
          float2 cv = *p;
          cv.x += bflo(yu[u]) * vv[u]; cv.y += bfhi(yu[u]) * vv[u];
          *p = cv;
        }
      }
      for (; i < nrec; i++) {
        unsigned rb = (unsigned)__shfl((int)currec, i, 64);
        float v = __uint_as_float(rb << 16);
        int rw0 = __shfl(rr, i, 64);
        unsigned yu0 = *(const unsigned*)&yb[(size_t)(rb >> 16) * 128 + lane * 2];
        float2* p = (float2*)&xg[(wave * 16 + rw0) * 128 + ((2 * lane) ^ ((rw0 & 7) << 4))];
        float2 cv = *p;
        cv.x += bflo(yu0) * v; cv.y += bfhi(yu0) * v;
        *p = cv;
      }
    }
  }

  // ---- epilogue: combine (acc in place) + BN partial sums
#pragma unroll
  for (int nt = 0; nt < 8; nt++) {
    int co = nt * 16 + (lane & 15);
    float s = 0.f, q = 0.f;
#pragma unroll
    for (int j = 0; j < 4; j++) {
      int r = wave * 16 + (lane >> 4) * 4 + j;
      float val = acc[nt][j] + xg[r * 128 + (co ^ ((r & 7) << 4))] * nrminv[r];
      acc[nt][j] = val;
      s += val; q += val * val;
    }
    s += __shfl_xor(s, 16, 64); s += __shfl_xor(s, 32, 64);
    q += __shfl_xor(q, 16, 64); q += __shfl_xor(q, 32, 64);
    if (lane < 16) {
      atomicAdd(&bnred[nt * 16 + lane], s);
      atomicAdd(&bnred[128 + nt * 16 + lane], q);
    }
  }
  __syncthreads();  // all gather-row reads done; xg reusable as bf16 tile

  // ---- pack bf16 into swizzled LDS tile, then one contiguous 16 KB coalesced store
  ushort_t* xto = (ushort_t*)xg;
#pragma unroll
  for (int nt = 0; nt < 8; nt++) {
    int co = nt * 16 + (lane & 15);
#pragma unroll
    for (int j = 0; j < 4; j++) {
      int r = wave * 16 + (lane >> 4) * 4 + j;
      xto[r * 128 + (co ^ ((r & 7) << 4))] = f2bf(acc[nt][j]);
    }
  }
  __syncthreads();
#pragma unroll
  for (int it = 0; it < 4; it++) {
    int q8 = (it * 256 + tid) * 8;  // ushort index in 64x128 tile
    int r = q8 >> 7, c = q8 & 127;
    uint4 vv = *(const uint4*)&xto[r * 128 + (c ^ ((r & 7) << 4))];
    *(uint4*)&XTB[((size_t)t0) * 128 + q8] = vv;
  }
  unsafeAtomicAdd(&BNP[(blk & 63) * 256 + tid], bnred[tid]);
}

// ---------- K8: reduce BN partials -> per-channel scale/shift ----------
__global__ void k_bnfin(const float* __restrict__ BNP, const float* __restrict__ gamma,
                        const float* __restrict__ beta, float* __restrict__ ss) {
  int c = threadIdx.x;  // 128
  float s = 0.f, q = 0.f;
#pragma unroll 4
  for (int k = 0; k < 64; k++) {
    s += BNP[k * 256 + c];
    q += BNP[k * 256 + 128 + c];
  }
  float n = (float)(BB * NN);
  float mean = s / n;
  float var = q / n - mean * mean;
  float sc = gamma[c] * rsqrtf(var + BNEPS);
  ss[c] = sc;
  ss[128 + c] = beta[c] - mean * sc;
}

// ---------- K9: conf + weight + fused x_act; 8192 blocks x 4 passes, XCD-aligned ----------
__global__ __launch_bounds__(256) void k_conf(const ushort_t* __restrict__ XTB, const float* __restrict__ ss,
                                              const float* __restrict__ confw, const float* __restrict__ confb,
                                              float* __restrict__ conf_out, float* __restrict__ wgt,
                                              float* __restrict__ xa) {
  int blk = blockIdx.x;                       // 8192
  int xcd = blk & 7, lblk = blk >> 3;         // XCD k reads batches [k*8, k*8+8) (matches k_xt writes)
  int l32 = threadIdx.x & 31, tok8 = threadIdx.x >> 5;
  int c0 = l32 * 4;
  const float4 sc = *(const float4*)&ss[c0];
  const float4 sh = *(const float4*)&ss[128 + c0];
  const float4 cw = *(const float4*)&confw[c0];
  const float cb0 = confb[0];
#pragma unroll 1
  for (int pass = 0; pass < 4; pass++) {
    int p = xcd * 32768 + lblk * 32 + pass * 8 + tok8;
    const uint2 pw = *(const uint2*)&XTB[(size_t)p * 128 + c0];
    float v0 = bflo(pw.x) * sc.x + sh.x;
    float v1 = bfhi(pw.x) * sc.y + sh.y;
    float v2 = bflo(pw.y) * sc.z + sh.z;
    float v3 = bfhi(pw.y) * sc.w + sh.w;
    float4 xo;
    xo.x = fmaxf(v0, 0.f); xo.y = fmaxf(v1, 0.f);
    xo.z = fmaxf(v2, 0.f); xo.w = fmaxf(v3, 0.f);
    *(float4*)&xa[(size_t)p * 128 + c0] = xo;
    float s = v0 * cw.x + v1 * cw.y + v2 * cw.z + v3 * cw.w;
#pragma unroll
    for (int off = 16; off; off >>= 1) s += __shfl_down(s, off, 32);
    if (l32 == 0) {
      float cf = s + cb0;
      conf_out[p] = cf;
      wgt[p] = __expf(cf);
    }
  }
}

// ---------- K10: cluster GATHER + fused awd (round-7 proven body: direct loads) ----------
__global__ __launch_bounds__(256) void k_cluster(const ushort_t* __restrict__ XTB, const float* __restrict__ ss,
                                                 const float* __restrict__ wgt, const float* __restrict__ aw,
                                                 const unsigned* __restrict__ pck32,
                                                 const unsigned* __restrict__ list32,
                                                 float* __restrict__ xd, float* __restrict__ awd,
                                                 int* __restrict__ maxb) {
  __shared__ float smax[4];
  int blk = blockIdx.x;                       // 4096
  int xcd = blk & 7, lblk = blk >> 3;         // XCD k owns cells [k*8192, +8192)
  int wave = threadIdx.x >> 6, lane = threadIdx.x & 63;
  int wbase = xcd * 8192 + lblk * 16 + wave * 4;
  int b = wbase >> 10;                        // all 16 cells of the block in one batch
  const float* wb = wgt + ((size_t)b << 12);
  const float* awb = aw + ((size_t)b << 12);
  const ushort_t* xtb = XTB + (((size_t)b) << 19);  // b*4096*128 ushorts
  const float2 sc = *(const float2*)&ss[2 * lane];
  const float2 sh = *(const float2*)&ss[128 + 2 * lane];
  float mymax = 0.f;
#pragma unroll 1
  for (int k = 0; k < 4; k++) {
    int wid = wbase + k;
    unsigned v = pck32[wid];
    int o = (int)(v >> 16), n = (int)(v & 0xffffu) - o;
    const unsigned* lp = list32 + ((size_t)b << 12) + o;
    float s0 = 0.f, s1 = 0.f, sv = 0.f;
    int i = 0;
    for (; i + 2 <= n; i += 2) {
      unsigned r0 = lp[i], r1 = lp[i + 1];
      int i0 = r0 >> 16, i1 = r1 >> 16;
      float v0 = wb[i0], v1 = wb[i1];
      unsigned p0 = *(const unsigned*)&xtb[(size_t)i0 * 128 + 2 * lane];
      unsigned p1 = *(const unsigned*)&xtb[(size_t)i1 * 128 + 2 * lane];
      s0 += (bflo(p0) * sc.x + sh.x) * v0 + (bflo(p1) * sc.x + sh.x) * v1;
      s1 += (bfhi(p0) * sc.y + sh.y) * v0 + (bfhi(p1) * sc.y + sh.y) * v1;
      sv += v0 + v1;
    }
    if (i < n) {
      unsigned r0 = lp[i];
      int i0 = r0 >> 16;
      float v0 = wb[i0];
      unsigned p0 = *(const unsigned*)&xtb[(size_t)i0 * 128 + 2 * lane];
      s0 += (bflo(p0) * sc.x + sh.x) * v0;
      s1 += (bfhi(p0) * sc.y + sh.y) * v0;
      sv += v0;
    }
    float inv = 1.f / (sv + EPSF);
    float2 o2; o2.x = fmaxf(s0 * inv, 0.f); o2.y = fmaxf(s1 * inv, 0.f);
    *(float2*)&xd[(size_t)wid * 128 + 2 * lane] = o2;

    // fused agg_weight_down (pre-norm) for this cell's points (direct loads)
    for (int kk = lane; kk < n; kk += 64) {
      unsigned rec = lp[kk];
      int idx = rec >> 16, pp = rec & 0xffffu;
      float a = awb[pp] * wb[idx] * inv;
      awd[(b << 12) + pp] = a;
      mymax = fmaxf(mymax, a);
    }
  }
#pragma unroll
  for (int off = 32; off; off >>= 1) mymax = fmaxf(mymax, __shfl_down(mymax, off, 64));
  if (lane == 0) smax[wave] = mymax;
  __syncthreads();
  if (threadIdx.x == 0) {
    float m = fmaxf(fmaxf(smax[0], smax[1]), fmaxf(smax[2], smax[3]));
    atomicMax(&maxb[b], __float_as_int(m));  // awd > 0 always
  }
}

// ---------- K11: normalize awd ----------
__global__ __launch_bounds__(256) void k_awdnorm(float* __restrict__ awd, const int* __restrict__ maxb) {
  int p = blockIdx.x * 256 + threadIdx.x;
  int b = p >> 12;
  awd[p] = awd[p] / __int_as_float(maxb[b]);
}

extern "C" void kernel_launch(void* const* d_in, const int* in_sizes, int n_in,
                              void* d_out, int out_size, void* d_ws, size_t ws_size,
                              hipStream_t stream) {
  (void)in_sizes; (void)n_in; (void)out_size;
  const float* x      = (const float*)d_in[0];
  const float* loc    = (const float*)d_in[1];
  const int*   idxagg = (const int*)  d_in[2];
  const float* aw     = (const float*)d_in[3];
  const float* convw  = (const float*)d_in[4];
  const float* convb  = (const float*)d_in[5];
  const float* skipw  = (const float*)d_in[6];
  const float* gamma  = (const float*)d_in[7];
  const float* beta   = (const float*)d_in[8];
  const float* confw  = (const float*)d_in[9];
  const float* confb  = (const float*)d_in[10];

  char* ws = (char*)d_ws;
  // XMB (padded 66x66 bf16 map, 35,684,352 B) aliases XTB: map is dead before k_xt writes XTB.
  ushort_t* XTB   = (ushort_t*)(ws + 0);          // 67,108,864 (bf16 xt)
  ushort_t* XMB   = (ushort_t*)(ws + 0);          // alias
  ushort_t* Y     = (ushort_t*)(ws + 67108864);   // 16,777,216 (bf16 conv out)
  ushort_t* WT    = (ushort_t*)(ws + 83886080);   // 147,456
  ushort_t* SWT   = (ushort_t*)(ws + 84033536);   // 16,384
  // ---- contiguous zero-init region [84,049,920 .. 87,524,352) = 3,474,432 B
  unsigned* PCK64 = (unsigned*)(ws + 84049920);   // 1,048,576  (off<<16 | cursor)
  unsigned* PCKT  = (unsigned*)(ws + 85098496);   // 1,048,576
  unsigned* PCK32 = (unsigned*)(ws + 86147072);   // 262,144
  float*    NRM   = (float*)  (ws + 86409216);    // 1,048,576
  float*    BNP   = (float*)  (ws + 87457792);    // 65,536
  int*      MAXB  = (int*)    (ws + 87523328);    // 1,024 (256 used)
  // ---- end zero region (k_zero covers through +3,477,504; 3072 B tail into LIST64 is
  //      harmless: LIST64 is fully overwritten by k_fill before any read)
  ushort_t* LIST64= (ushort_t*)(ws + 87524352);   // 524,288    (token idx u16)
  unsigned* LISTT = (unsigned*)(ws + 88048640);   // 1,048,576  (cell<<16 | aw-bf16)
  unsigned* LIST32= (unsigned*)(ws + 89097216);   // 1,048,576  (idx<<16 | point)
  float*    WGT   = (float*)  (ws + 90145792);    // 1,048,576
  float*    SS    = (float*)  (ws + 91194368);    // 1,024
  if (ws_size < 91195392) return;  // insufficient workspace -> visible failure

  float* out    = (float*)d_out;
  float* O_XD   = out;               // x_down: 8,388,608 floats
  float* O_IDX  = out + 8388608;     // idx_agg_down (as float): 262,144
  float* O_AWD  = out + 8650752;     // agg_weight_down: 262,144
  float* XA     = out + 8912896;     // x_act: 33,554,432 floats
  float* O_CONF = out + 42467328;    // conf: 262,144

  k_zero   <<<849,   256, 0, stream>>>((uint4*)(ws + 84049920));  // 3,477,504 B
  k_prep   <<<1344,  256, 0, stream>>>(loc, idxagg, aw, O_IDX, PCK64, PCK32, PCKT, NRM,
                                       convw, skipw, WT, SWT);
  k_scan   <<<192,   256, 0, stream>>>(PCK64, PCKT, PCK32);
  k_fill   <<<2064,  256, 0, stream>>>(loc, idxagg, aw, PCK64, PCKT, PCK32, LIST64, LISTT, LIST32, XMB);
  k_t2m    <<<8192,  256, 0, stream>>>(x, PCK64, LIST64, XMB);
  k_conv   <<<512,   256, 0, stream>>>(XMB, WT, convb, Y);
  k_xt     <<<4096,  256, 0, stream>>>(x, SWT, Y, LISTT, PCKT, NRM, XTB, BNP);
  k_bnfin  <<<1,     128, 0, stream>>>(BNP, gamma, beta, SS);
  k_conf   <<<8192,  256, 0, stream>>>(XTB, SS, confw, confb, O_CONF, WGT, XA);
  k_cluster<<<4096,  256, 0, stream>>>(XTB, SS, WGT, aw, PCK32, LIST32, O_XD, O_AWD, MAXB);
  k_awdnorm<<<1024,  256, 0, stream>>>(O_AWD, MAXB);
}

// Round 11
// 327.453 us; speedup vs baseline: 1.0577x; 1.0577x over previous
//
#include <hip/hip_runtime.h>

// Problem constants (setup_inputs: B=64, N=4096, C=64, Cout=128, H=W=64)
#define BB 64
#define NN 4096
#define CCH 64
#define CO 128
#define HH 64
#define WW 64
#define H2 32
#define W2 32
#define EPSF 1e-6f
#define BNEPS 1e-5f

typedef unsigned short ushort_t;
using bf8  = __attribute__((ext_vector_type(8))) short;   // 8 bf16 (4 VGPRs)
using f32x4 = __attribute__((ext_vector_type(4))) float;  // MFMA accumulator
using ef4   = __attribute__((ext_vector_type(4))) float;  // ext-vector for nontemporal stores
using ef2   = __attribute__((ext_vector_type(2))) float;

__device__ inline ushort_t f2bf(float f) {
  unsigned u = __float_as_uint(f);
  unsigned r = (u + 0x7fffu + ((u >> 16) & 1u)) >> 16;  // RNE
  return (ushort_t)r;
}
__device__ inline float bflo(unsigned u) { return __uint_as_float(u << 16); }
__device__ inline float bfhi(unsigned u) { return __uint_as_float(u & 0xffff0000u); }

__device__ inline void gload_lds16(const void* src, void* ldsdst) {
  __builtin_amdgcn_global_load_lds((const __attribute__((address_space(1))) void*)src,
                                   (__attribute__((address_space(3))) void*)ldsdst, 16, 0, 0);
}

__device__ inline void cells_from_loc(float lx, float ly, int& c64, int& c32) {
  lx = fminf(fmaxf(lx, -1.f), 1.f) * 0.5f + 0.5f;
  ly = fminf(fmaxf(ly, -1.f), 1.f) * 0.5f + 0.5f;
  int cx = (int)fminf(fmaxf(rintf(lx * (WW - 1)), 0.f), (float)(WW - 1));
  int cy = (int)fminf(fmaxf(rintf(ly * (HH - 1)), 0.f), (float)(HH - 1));
  c64 = cx + cy * WW;
  int cx2 = (int)fminf(fmaxf(rintf(lx * (W2 - 1)), 0.f), (float)(W2 - 1));
  int cy2 = (int)fminf(fmaxf(rintf(ly * (H2 - 1)), 0.f), (float)(H2 - 1));
  c32 = cx2 + cy2 * W2;
}

// ---------- K0: fast zero of the metadata region ----------
__global__ __launch_bounds__(256) void k_zero(uint4* __restrict__ p) {
  p[blockIdx.x * 256 + threadIdx.x] = make_uint4(0u, 0u, 0u, 0u);  // 849*256*16 B
}

// ---------- K1: cells + idx_agg_down output + counts + NRM; blocks >=1024: bf16 weights ----------
__global__ __launch_bounds__(256) void k_prep(const float* __restrict__ loc, const int* __restrict__ idxagg,
                                              const float* __restrict__ aw,
                                              float* __restrict__ idx_out,
                                              unsigned* __restrict__ pck64, unsigned* __restrict__ pck32,
                                              unsigned* __restrict__ pckT, float* __restrict__ nrm,
                                              const float* __restrict__ convw, const float* __restrict__ skipw,
                                              ushort_t* __restrict__ wT, ushort_t* __restrict__ swT) {
  int blk = blockIdx.x;  // 1344
  if (blk >= 1024) {     // fused weight prep (320 blocks' worth)
    int e = (blk - 1024) * 256 + threadIdx.x;  // < 81920
    if (e < 9 * CCH * CO) {
      int co = e & 127, k = e >> 7;
      wT[co * 576 + k] = f2bf(convw[k * CO + co]);
    } else {
      int e2 = e - 9 * CCH * CO;
      int co = e2 & 127, k = e2 >> 7;
      swT[co * 64 + k] = f2bf(skipw[k * CO + co]);
    }
    return;
  }
  int i = blk * 256 + threadIdx.x;  // exactly B*N = 262144
  int b = i >> 12;
  int c64, c2;
  cells_from_loc(loc[2 * i], loc[2 * i + 1], c64, c2);
  __builtin_nontemporal_store((float)c2, &idx_out[i]);  // write-once output
  atomicAdd(&pck64[(b << 12) + c64], 1u);
  atomicAdd(&pck32[(b << 10) + c2], 1u);
  atomicAdd(&pckT[(b << 12) + idxagg[i]], 1u);
  unsafeAtomicAdd(&nrm[(b << 12) + idxagg[i]], aw[i]);
}

// ---------- scan helper: in-place exclusive scan; buf[i]: count -> (off<<16)|off ----------
__device__ void block_exscan_pack(unsigned* __restrict__ buf, int L) {
  __shared__ int partial[256];
  int tid = threadIdx.x;
  int per = L >> 8;
  int base = tid * per;
  int s = 0;
  for (int i = 0; i < per; i++) s += (int)buf[base + i];
  __syncthreads();
  partial[tid] = s;
  __syncthreads();
  for (int d = 1; d < 256; d <<= 1) {
    int v = (tid >= d) ? partial[tid - d] : 0;
    __syncthreads();
    partial[tid] += v;
    __syncthreads();
  }
  int run = (tid == 0) ? 0 : partial[tid - 1];
  for (int i = 0; i < per; i++) {
    int n = (int)buf[base + i];
    buf[base + i] = ((unsigned)run << 16) | (unsigned)run;
    run += n;
  }
}

// ---------- K3: per-batch prefix scans; one block per (batch, sort-kind) ----------
__global__ __launch_bounds__(256) void k_scan(unsigned* __restrict__ pck64, unsigned* __restrict__ pckT,
                                              unsigned* __restrict__ pck32) {
  int b = blockIdx.x / 3, kind = blockIdx.x - 3 * (blockIdx.x / 3);  // 192 blocks
  if (kind == 0)      block_exscan_pack(pck64 + ((size_t)b << 12), 4096);
  else if (kind == 1) block_exscan_pack(pckT + ((size_t)b << 12), 4096);
  else                block_exscan_pack(pck32 + ((size_t)b << 10), 1024);
}

// ---------- K4: fill sorted packed lists; blocks >=1024: zero map borders ----------
__global__ __launch_bounds__(256) void k_fill(const float* __restrict__ loc, const int* __restrict__ idxagg,
                                              const float* __restrict__ aw,
                                              unsigned* __restrict__ pck64, unsigned* __restrict__ pckT,
                                              unsigned* __restrict__ pck32,
                                              ushort_t* __restrict__ list64, unsigned* __restrict__ listT,
                                              unsigned* __restrict__ list32, ushort_t* __restrict__ xmb) {
  int blk = blockIdx.x;  // 2064
  if (blk >= 1024) {     // fused border zero (1040 blocks' worth)
    int t = (blk - 1024) * 256 + threadIdx.x;  // exactly 64*260*16 = 266240
    int q = t & 15;
    int cell = (t >> 4) % 260;
    int b = t / (260 * 16);
    int r, c;
    if (cell < 66)       { r = 0;  c = cell; }
    else if (cell < 132) { r = 65; c = cell - 66; }
    else if (cell < 196) { r = cell - 132 + 1; c = 0; }
    else                 { r = cell - 196 + 1; c = 65; }
    *(uint2*)&xmb[(((size_t)(b * 66 + r)) * 66 + c) * 64 + q * 4] = make_uint2(0u, 0u);
    return;
  }
  int i = blk * 256 + threadIdx.x;  // B*N
  int b = i >> 12, p = i & 4095;
  int c64, c2;
  cells_from_loc(loc[2 * i], loc[2 * i + 1], c64, c2);
  int idx = idxagg[i];
  unsigned pos = atomicAdd(&pck64[(b << 12) + c64], 1u) & 0xffffu;
  list64[(b << 12) + pos] = (ushort_t)idx;                       // token index
  pos = atomicAdd(&pckT[(b << 12) + idx], 1u) & 0xffffu;
  listT[(b << 12) + pos] = ((unsigned)c2 << 16) | (unsigned)f2bf(aw[i]);  // {cell, aw-bf16}
  pos = atomicAdd(&pck32[(b << 10) + c2], 1u) & 0xffffu;
  list32[(b << 12) + pos] = ((unsigned)idx << 16) | (unsigned)p;          // {token idx, point id}
}

// ---------- K5: token2map GATHER; 8 cells/wave; register-resident records via shfl ----------
// (uniform-index, full-exec shfl only — the validated pattern)
__global__ __launch_bounds__(256) void k_t2m(const float* __restrict__ x,
                                             const unsigned* __restrict__ pck64,
                                             const ushort_t* __restrict__ list64, ushort_t* __restrict__ xmb) {
  int blk = blockIdx.x;                       // 8192
  int xcd = blk & 7, lblk = blk >> 3;         // XCD k owns batches [k*8, k*8+8)
  int wave = threadIdx.x >> 6, lane = threadIdx.x & 63;
  int cbase = xcd * 32768 + lblk * 32 + wave * 8;   // 8 consecutive cells per wave (one batch)
  int b = cbase >> 12;
  // 8 cell descriptors via 2 wave-uniform 16B loads
  unsigned pcks[8];
  *(uint4*)&pcks[0] = *(const uint4*)&pck64[cbase];
  *(uint4*)&pcks[4] = *(const uint4*)&pck64[cbase + 4];
  int o0 = (int)(pcks[0] >> 16);
  int total = (int)(pcks[7] & 0xffffu) - o0;  // low16 post-fill = end cursor
  const ushort_t* lp0 = list64 + ((size_t)b << 12) + o0;
  int myrec = (lane < total) ? (int)lp0[lane] : 0;  // ALL 8 cells' records in one coalesced load
  const float* xb = x + ((size_t)b << 18);
#pragma unroll 1
  for (int k = 0; k < 8; k++) {
    int off = (int)(pcks[k] >> 16) - o0;
    int n = (int)(pcks[k] & 0xffffu) - (int)(pcks[k] >> 16);
    float s0 = 0.f, s1 = 0.f, s2 = 0.f, s3 = 0.f;
    int i = 0;
    for (; i + 4 <= n; i += 4) {
      int j = off + i;  // uniform
      int i0 = (j     < 64) ? __shfl(myrec, j,     64) : (int)lp0[j];
      int i1 = (j + 1 < 64) ? __shfl(myrec, j + 1, 64) : (int)lp0[j + 1];
      int i2 = (j + 2 < 64) ? __shfl(myrec, j + 2, 64) : (int)lp0[j + 2];
      int i3 = (j + 3 < 64) ? __shfl(myrec, j + 3, 64) : (int)lp0[j + 3];
      s0 += xb[(size_t)i0 * 64 + lane];
      s1 += xb[(size_t)i1 * 64 + lane];
      s2 += xb[(size_t)i2 * 64 + lane];
      s3 += xb[(size_t)i3 * 64 + lane];
    }
    for (; i < n; i++) {
      int j = off + i;
      int i0 = (j < 64) ? __shfl(myrec, j, 64) : (int)lp0[j];
      s0 += xb[(size_t)i0 * 64 + lane];
    }
    float avg = (s0 + s1 + s2 + s3) / ((float)n + EPSF);
    int cell = (cbase + k) & 4095;
    int r = cell >> 6, cc = cell & 63;
    xmb[(((size_t)(b * 66 + r + 1)) * 66 + cc + 1) * 64 + lane] = f2bf(avg);
  }
}

// ---------- K6: conv 3x3 stride2 pad1 implicit GEMM; bf16 Y out (verified) ----------
__global__ __launch_bounds__(256) void k_conv(const ushort_t* __restrict__ xmb, const ushort_t* __restrict__ wT,
                                              const float* __restrict__ cb, ushort_t* __restrict__ y) {
  __shared__ ushort_t A[2][4096];
  const int tid = threadIdx.x;
  const int wave = tid >> 6, lane = tid & 63;
  const int m0 = blockIdx.x * 128;

  f32x4 acc[2][8];
  {
    float bv[8];
#pragma unroll
    for (int nt = 0; nt < 8; nt++) bv[nt] = cb[nt * 16 + (lane & 15)];
#pragma unroll
    for (int mt = 0; mt < 2; mt++)
#pragma unroll
      for (int nt = 0; nt < 8; nt++) {
        f32x4 a; a[0] = bv[nt]; a[1] = bv[nt]; a[2] = bv[nt]; a[3] = bv[nt];
        acc[mt][nt] = a;
      }
  }

  const int srcslot = (((lane & 3) ^ ((lane >> 3) & 3))) * 8;
  int sb[2], soy[2], sox[2];
#pragma unroll
  for (int q = 0; q < 2; q++) {
    int r = wave * 32 + q * 16 + (lane >> 2);
    int s = m0 + r;
    sb[q] = s >> 10; soy[q] = (s >> 5) & 31; sox[q] = s & 31;
  }

  auto stage = [&](int ks, int buf) {
    int kp = ks >> 1, ci0 = (ks & 1) * 32;
    int ky = kp / 3, kx = kp - ky * 3;
#pragma unroll
    for (int q = 0; q < 2; q++) {
      int iy = 2 * soy[q] + ky, ix = 2 * sox[q] + kx;
      const ushort_t* src = xmb + (((size_t)sb[q] * 66 + iy) * 66 + ix) * 64 + ci0 + srcslot;
      gload_lds16(src, &A[buf][(wave * 32 + q * 16) * 32]);
    }
  };

  stage(0, 0);
  const int rdslotx = (lane >> 1) & 3;
  for (int ks = 0; ks < 18; ks++) {
    int buf = ks & 1;
    __syncthreads();
    if (ks < 17) stage(ks + 1, buf ^ 1);
    bf8 a[2];
#pragma unroll
    for (int mt = 0; mt < 2; mt++) {
      int r = wave * 32 + mt * 16 + (lane & 15);
      int slot = (lane >> 4) ^ rdslotx;
      a[mt] = *(const bf8*)&A[buf][r * 32 + slot * 8];
    }
    int k0 = ks * 32 + (lane >> 4) * 8;
#pragma unroll
    for (int nt = 0; nt < 8; nt++) {
      int co = nt * 16 + (lane & 15);
      bf8 bbf = *(const bf8*)&wT[co * 576 + k0];
      acc[0][nt] = __builtin_amdgcn_mfma_f32_16x16x32_bf16(a[0], bbf, acc[0][nt], 0, 0, 0);
      acc[1][nt] = __builtin_amdgcn_mfma_f32_16x16x32_bf16(a[1], bbf, acc[1][nt], 0, 0, 0);
    }
  }
#pragma unroll
  for (int mt = 0; mt < 2; mt++)
#pragma unroll
    for (int nt = 0; nt < 8; nt++) {
      int co = nt * 16 + (lane & 15);
#pragma unroll
      for (int j = 0; j < 4; j++) {
        int srow = m0 + wave * 32 + mt * 16 + (lane >> 4) * 4 + j;
        y[(size_t)srow * 128 + co] = f2bf(acc[mt][nt][j]);
      }
    }
}

// ---------- K7: FUSED xt = gather_m2t(y)/nrm + x@skip_w + BN partials; bf16 XT out ----------
__global__ __launch_bounds__(256) void k_xt(const float* __restrict__ x, const ushort_t* __restrict__ swT,
                                            const ushort_t* __restrict__ y,
                                            const unsigned* __restrict__ listT, const unsigned* __restrict__ pckT,
                                            const float* __restrict__ nrm,
                                            ushort_t* __restrict__ XTB, float* __restrict__ BNP) {
  __shared__ float xg[64 * 128];   // 32 KB: x staging (first 16 KB) -> gather accum -> bf16 out (alias)
  __shared__ float nrminv[64];
  __shared__ float bnred[256];
  const int tid = threadIdx.x, wave = tid >> 6, lane = tid & 63;
  int blk = blockIdx.x;                       // 4096
  int sblk = (blk & 7) * 512 + (blk >> 3);    // XCD swizzle (8 batches per XCD)
  const int t0 = sblk * 64;
  const int b = t0 >> 12, lt0 = t0 & 4095;

  // ---- issue-early: token offsets (independent of everything below)
  int myoff = 0;
  {
    int gtok = lt0 + wave * 16 + lane;
    if (lane <= 16) myoff = (gtok >= NN) ? NN : (int)(pckT[(b << 12) + gtok] >> 16);
  }

  // ---- stage x tile (64x64 f32 = 16 KB), 16 chunks of 4 rows, swizzled 16B slots
#pragma unroll
  for (int q = 0; q < 4; q++) {
    int ch = wave * 4 + q;
    int r = ch * 4 + (lane >> 4);
    int sp = lane & 15;
    const float* src = x + ((size_t)(t0 + r)) * 64 + ((sp ^ (r & 7)) << 2);
    gload_lds16(src, (char*)xg + ch * 1024);
  }
  if (tid < 64) nrminv[tid] = 1.f / (nrm[(b << 12) + lt0 + tid] + EPSF);
  bnred[tid] = 0.f;
  __syncthreads();

  // ---- A fragments (f32 -> bf16)
  bf8 afr[2];
  {
    int r = wave * 16 + (lane & 15);
#pragma unroll
    for (int ks = 0; ks < 2; ks++) {
      int cs = ks * 4 + (lane >> 4);
      const float4 f0 = *(const float4*)&xg[r * 64 + (((2 * cs) ^ (r & 7)) << 2)];
      const float4 f1 = *(const float4*)&xg[r * 64 + (((2 * cs + 1) ^ (r & 7)) << 2)];
      bf8 v;
      v[0] = (short)f2bf(f0.x); v[1] = (short)f2bf(f0.y);
      v[2] = (short)f2bf(f0.z); v[3] = (short)f2bf(f0.w);
      v[4] = (short)f2bf(f1.x); v[5] = (short)f2bf(f1.y);
      v[6] = (short)f2bf(f1.z); v[7] = (short)f2bf(f1.w);
      afr[ks] = v;
    }
  }

  // ---- skip GEMM: wave computes rows [wave*16, wave*16+16) x 128 cols
  f32x4 acc[8];
#pragma unroll
  for (int nt = 0; nt < 8; nt++) { f32x4 z; z[0] = 0; z[1] = 0; z[2] = 0; z[3] = 0; acc[nt] = z; }
#pragma unroll
  for (int ks = 0; ks < 2; ks++)
#pragma unroll
    for (int nt = 0; nt < 8; nt++) {
      int co = nt * 16 + (lane & 15);
      bf8 bbf = *(const bf8*)&swT[co * 64 + ks * 32 + (lane >> 4) * 8];
      acc[nt] = __builtin_amdgcn_mfma_f32_16x16x32_bf16(afr[ks], bbf, acc[nt], 0, 0, 0);
    }

  __syncthreads();  // all waves' fragment reads done; xg reusable as gather accum

  // ---- prefetch chunk-0 records, then zero own gather rows
  int pbeg = __shfl(myoff, 0, 64), pend = __shfl(myoff, 16, 64);
  const unsigned* ltb = listT + ((size_t)b << 12);
  unsigned rec = (pbeg + lane < pend) ? ltb[pbeg + lane] : 0u;
#pragma unroll
  for (int rr = 0; rr < 16; rr++) {
    *(float2*)&xg[(wave * 16 + rr) * 128 + ((2 * lane) ^ ((rr & 7) << 4))] = make_float2(0.f, 0.f);
  }

  // ---- m2t gather: double-buffered record chunks; 4-deep y-row pipeline
  {
    const ushort_t* yb = y + ((size_t)b << 17);  // b*1024*128 ushorts
    for (int chunk = pbeg; chunk < pend; chunk += 64) {
      int pid = chunk + lane;
      unsigned currec = rec;
      if (chunk + 64 < pend) rec = (pid + 64 < pend) ? ltb[pid + 64] : 0u;  // prefetch next
      int rr = 0;
#pragma unroll
      for (int j = 1; j <= 16; j++) rr += (pid >= __shfl(myoff, j, 64)) ? 1 : 0;
      int nrec = min(64, pend - chunk);
      int i = 0;
      for (; i + 4 <= nrec; i += 4) {
        unsigned yu[4]; float vv[4]; int rw[4];
#pragma unroll
        for (int u = 0; u < 4; u++) {
          unsigned rb = (unsigned)__shfl((int)currec, i + u, 64);
          vv[u] = __uint_as_float(rb << 16);
          rw[u] = __shfl(rr, i + u, 64);
          yu[u] = *(const unsigned*)&yb[(size_t)(rb >> 16) * 128 + lane * 2];
        }
#pragma unroll
        for (int u = 0; u < 4; u++) {
          float2* p = (float2*)&xg[(wave * 16 + rw[u]) * 128 + ((2 * lane) ^ ((rw[u] & 7) << 4))];
          float2 cv = *p;
          cv.x += bflo(yu[u]) * vv[u]; cv.y += bfhi(yu[u]) * vv[u];
          *p = cv;
        }
      }
      for (; i < nrec; i++) {
        unsigned rb = (unsigned)__shfl((int)currec, i, 64);
        float v = __uint_as_float(rb << 16);
        int rw0 = __shfl(rr, i, 64);
        unsigned yu0 = *(const unsigned*)&yb[(size_t)(rb >> 16) * 128 + lane * 2];
        float2* p = (float2*)&xg[(wave * 16 + rw0) * 128 + ((2 * lane) ^ ((rw0 & 7) << 4))];
        float2 cv = *p;
        cv.x += bflo(yu0) * v; cv.y += bfhi(yu0) * v;
        *p = cv;
      }
    }
  }

  // ---- epilogue: combine (acc in place) + BN partial sums
#pragma unroll
  for (int nt = 0; nt < 8; nt++) {
    int co = nt * 16 + (lane & 15);
    float s = 0.f, q = 0.f;
#pragma unroll
    for (int j = 0; j < 4; j++) {
      int r = wave * 16 + (lane >> 4) * 4 + j;
      float val = acc[nt][j] + xg[r * 128 + (co ^ ((r & 7) << 4))] * nrminv[r];
      acc[nt][j] = val;
      s += val; q += val * val;
    }
    s += __shfl_xor(s, 16, 64); s += __shfl_xor(s, 32, 64);
    q += __shfl_xor(q, 16, 64); q += __shfl_xor(q, 32, 64);
    if (lane < 16) {
      atomicAdd(&bnred[nt * 16 + lane], s);
      atomicAdd(&bnred[128 + nt * 16 + lane], q);
    }
  }
  __syncthreads();  // all gather-row reads done; xg reusable as bf16 tile

  // ---- pack bf16 into swizzled LDS tile, then one contiguous 16 KB coalesced store
  ushort_t* xto = (ushort_t*)xg;
#pragma unroll
  for (int nt = 0; nt < 8; nt++) {
    int co = nt * 16 + (lane & 15);
#pragma unroll
    for (int j = 0; j < 4; j++) {
      int r = wave * 16 + (lane >> 4) * 4 + j;
      xto[r * 128 + (co ^ ((r & 7) << 4))] = f2bf(acc[nt][j]);
    }
  }
  __syncthreads();
#pragma unroll
  for (int it = 0; it < 4; it++) {
    int q8 = (it * 256 + tid) * 8;  // ushort index in 64x128 tile
    int r = q8 >> 7, c = q8 & 127;
    uint4 vv = *(const uint4*)&xto[r * 128 + (c ^ ((r & 7) << 4))];
    *(uint4*)&XTB[((size_t)t0) * 128 + q8] = vv;
  }
  unsafeAtomicAdd(&BNP[(blk & 63) * 256 + tid], bnred[tid]);
}

// ---------- K8: reduce BN partials -> per-channel scale/shift ----------
__global__ void k_bnfin(const float* __restrict__ BNP, const float* __restrict__ gamma,
                        const float* __restrict__ beta, float* __restrict__ ss) {
  int c = threadIdx.x;  // 128
  float s = 0.f, q = 0.f;
#pragma unroll 4
  for (int k = 0; k < 64; k++) {
    s += BNP[k * 256 + c];
    q += BNP[k * 256 + 128 + c];
  }
  float n = (float)(BB * NN);
  float mean = s / n;
  float var = q / n - mean * mean;
  float sc = gamma[c] * rsqrtf(var + BNEPS);
  ss[c] = sc;
  ss[128 + c] = beta[c] - mean * sc;
}

// ---------- K9: conf + weight + fused x_act; 8192 blocks x 4 passes, XCD-aligned ----------
// XA stored nontemporal (write-once, 128 MB) to keep XTB resident in L2 for k_cluster.
__global__ __launch_bounds__(256) void k_conf(const ushort_t* __restrict__ XTB, const float* __restrict__ ss,
                                              const float* __restrict__ confw, const float* __restrict__ confb,
                                              float* __restrict__ conf_out, float* __restrict__ wgt,
                                              float* __restrict__ xa) {
  int blk = blockIdx.x;                       // 8192
  int xcd = blk & 7, lblk = blk >> 3;         // XCD k reads batches [k*8, k*8+8) (matches k_xt writes)
  int l32 = threadIdx.x & 31, tok8 = threadIdx.x >> 5;
  int c0 = l32 * 4;
  const float4 sc = *(const float4*)&ss[c0];
  const float4 sh = *(const float4*)&ss[128 + c0];
  const float4 cw = *(const float4*)&confw[c0];
  const float cb0 = confb[0];
#pragma unroll 1
  for (int pass = 0; pass < 4; pass++) {
    int p = xcd * 32768 + lblk * 32 + pass * 8 + tok8;
    const uint2 pw = *(const uint2*)&XTB[(size_t)p * 128 + c0];
    float v0 = bflo(pw.x) * sc.x + sh.x;
    float v1 = bfhi(pw.x) * sc.y + sh.y;
    float v2 = bflo(pw.y) * sc.z + sh.z;
    float v3 = bfhi(pw.y) * sc.w + sh.w;
    ef4 xo;
    xo[0] = fmaxf(v0, 0.f); xo[1] = fmaxf(v1, 0.f);
    xo[2] = fmaxf(v2, 0.f); xo[3] = fmaxf(v3, 0.f);
    __builtin_nontemporal_store(xo, (ef4*)&xa[(size_t)p * 128 + c0]);
    float s = v0 * cw.x + v1 * cw.y + v2 * cw.z + v3 * cw.w;
#pragma unroll
    for (int off = 16; off; off >>= 1) s += __shfl_down(s, off, 32);
    if (l32 == 0) {
      float cf = s + cb0;
      __builtin_nontemporal_store(cf, &conf_out[p]);  // write-once output
      wgt[p] = __expf(cf);                            // re-read by k_cluster: keep cacheable
    }
  }
}

// ---------- K10: cluster GATHER + fused awd; reversed lblk (starts on L2-hot XTB slabs) ----------
__global__ __launch_bounds__(256) void k_cluster(const ushort_t* __restrict__ XTB, const float* __restrict__ ss,
                                                 const float* __restrict__ wgt, const float* __restrict__ aw,
                                                 const unsigned* __restrict__ pck32,
                                                 const unsigned* __restrict__ list32,
                                                 float* __restrict__ xd, float* __restrict__ awd,
                                                 int* __restrict__ maxb) {
  __shared__ float smax[4];
  int blk = blockIdx.x;                       // 4096
  int xcd = blk & 7, lblk = 511 - (blk >> 3); // reversed: first blocks hit k_conf's last-read slabs
  int wave = threadIdx.x >> 6, lane = threadIdx.x & 63;
  int wbase = xcd * 8192 + lblk * 16 + wave * 4;
  int b = wbase >> 10;                        // all 16 cells of the block in one batch
  const float* wb = wgt + ((size_t)b << 12);
  const float* awb = aw + ((size_t)b << 12);
  const ushort_t* xtb = XTB + (((size_t)b) << 19);  // b*4096*128 ushorts
  const float2 sc = *(const float2*)&ss[2 * lane];
  const float2 sh = *(const float2*)&ss[128 + 2 * lane];
  float mymax = 0.f;
#pragma unroll 1
  for (int k = 0; k < 4; k++) {
    int wid = wbase + k;
    unsigned v = pck32[wid];
    int o = (int)(v >> 16), n = (int)(v & 0xffffu) - o;
    const unsigned* lp = list32 + ((size_t)b << 12) + o;
    float s0 = 0.f, s1 = 0.f, sv = 0.f;
    int i = 0;
    for (; i + 2 <= n; i += 2) {
      unsigned r0 = lp[i], r1 = lp[i + 1];
      int i0 = r0 >> 16, i1 = r1 >> 16;
      float v0 = wb[i0], v1 = wb[i1];
      unsigned p0 = *(const unsigned*)&xtb[(size_t)i0 * 128 + 2 * lane];
      unsigned p1 = *(const unsigned*)&xtb[(size_t)i1 * 128 + 2 * lane];
      s0 += (bflo(p0) * sc.x + sh.x) * v0 + (bflo(p1) * sc.x + sh.x) * v1;
      s1 += (bfhi(p0) * sc.y + sh.y) * v0 + (bfhi(p1) * sc.y + sh.y) * v1;
      sv += v0 + v1;
    }
    if (i < n) {
      unsigned r0 = lp[i];
      int i0 = r0 >> 16;
      float v0 = wb[i0];
      unsigned p0 = *(const unsigned*)&xtb[(size_t)i0 * 128 + 2 * lane];
      s0 += (bflo(p0) * sc.x + sh.x) * v0;
      s1 += (bfhi(p0) * sc.y + sh.y) * v0;
      sv += v0;
    }
    float inv = 1.f / (sv + EPSF);
    ef2 o2;
    o2[0] = fmaxf(s0 * inv, 0.f); o2[1] = fmaxf(s1 * inv, 0.f);
    __builtin_nontemporal_store(o2, (ef2*)&xd[(size_t)wid * 128 + 2 * lane]);  // write-once

    // fused agg_weight_down (pre-norm) for this cell's points (direct loads)
    for (int kk = lane; kk < n; kk += 64) {
      unsigned rec = lp[kk];
      int idx = rec >> 16, pp = rec & 0xffffu;
      float a = awb[pp] * wb[idx] * inv;
      awd[(b << 12) + pp] = a;    // re-read by k_awdnorm: keep cacheable
      mymax = fmaxf(mymax, a);
    }
  }
#pragma unroll
  for (int off = 32; off; off >>= 1) mymax = fmaxf(mymax, __shfl_down(mymax, off, 64));
  if (lane == 0) smax[wave] = mymax;
  __syncthreads();
  if (threadIdx.x == 0) {
    float m = fmaxf(fmaxf(smax[0], smax[1]), fmaxf(smax[2], smax[3]));
    atomicMax(&maxb[b], __float_as_int(m));  // awd > 0 always
  }
}

// ---------- K11: normalize awd ----------
__global__ __launch_bounds__(256) void k_awdnorm(float* __restrict__ awd, const int* __restrict__ maxb) {
  int p = blockIdx.x * 256 + threadIdx.x;
  int b = p >> 12;
  float v = awd[p] / __int_as_float(maxb[b]);
  __builtin_nontemporal_store(v, &awd[p]);  // final write-once output
}

extern "C" void kernel_launch(void* const* d_in, const int* in_sizes, int n_in,
                              void* d_out, int out_size, void* d_ws, size_t ws_size,
                              hipStream_t stream) {
  (void)in_sizes; (void)n_in; (void)out_size;
  const float* x      = (const float*)d_in[0];
  const float* loc    = (const float*)d_in[1];
  const int*   idxagg = (const int*)  d_in[2];
  const float* aw     = (const float*)d_in[3];
  const float* convw  = (const float*)d_in[4];
  const float* convb  = (const float*)d_in[5];
  const float* skipw  = (const float*)d_in[6];
  const float* gamma  = (const float*)d_in[7];
  const float* beta   = (const float*)d_in[8];
  const float* confw  = (const float*)d_in[9];
  const float* confb  = (const float*)d_in[10];

  char* ws = (char*)d_ws;
  // XMB (padded 66x66 bf16 map, 35,684,352 B) aliases XTB: map is dead before k_xt writes XTB.
  ushort_t* XTB   = (ushort_t*)(ws + 0);          // 67,108,864 (bf16 xt)
  ushort_t* XMB   = (ushort_t*)(ws + 0);          // alias
  ushort_t* Y     = (ushort_t*)(ws + 67108864);   // 16,777,216 (bf16 conv out)
  ushort_t* WT    = (ushort_t*)(ws + 83886080);   // 147,456
  ushort_t* SWT   = (ushort_t*)(ws + 84033536);   // 16,384
  // ---- contiguous zero-init region [84,049,920 .. 87,524,352) = 3,474,432 B
  unsigned* PCK64 = (unsigned*)(ws + 84049920);   // 1,048,576  (off<<16 | cursor)
  unsigned* PCKT  = (unsigned*)(ws + 85098496);   // 1,048,576
  unsigned* PCK32 = (unsigned*)(ws + 86147072);   // 262,144
  float*    NRM   = (float*)  (ws + 86409216);    // 1,048,576
  float*    BNP   = (float*)  (ws + 87457792);    // 65,536
  int*      MAXB  = (int*)    (ws + 87523328);    // 1,024 (256 used)
  // ---- end zero region (k_zero covers through +3,477,504; 3072 B tail into LIST64 is
  //      harmless: LIST64 is fully overwritten by k_fill before any read)
  ushort_t* LIST64= (ushort_t*)(ws + 87524352);   // 524,288    (token idx u16)
  unsigned* LISTT = (unsigned*)(ws + 88048640);   // 1,048,576  (cell<<16 | aw-bf16)
  unsigned* LIST32= (unsigned*)(ws + 89097216);   // 1,048,576  (idx<<16 | point)
  float*    WGT   = (float*)  (ws + 90145792);    // 1,048,576
  float*    SS    = (float*)  (ws + 91194368);    // 1,024
  if (ws_size < 91195392) return;  // insufficient workspace -> visible failure

  float* out    = (float*)d_out;
  float* O_XD   = out;               // x_down: 8,388,608 floats
  float* O_IDX  = out + 8388608;     // idx_agg_down (as float): 262,144
  float* O_AWD  = out + 8650752;     // agg_weight_down: 262,144
  float* XA     = out + 8912896;     // x_act: 33,554,432 floats
  float* O_CONF = out + 42467328;    // conf: 262,144

  k_zero   <<<849,   256, 0, stream>>>((uint4*)(ws + 84049920));  // 3,477,504 B
  k_prep   <<<1344,  256, 0, stream>>>(loc, idxagg, aw, O_IDX, PCK64, PCK32, PCKT, NRM,
                                       convw, skipw, WT, SWT);
  k_scan   <<<192,   256, 0, stream>>>(PCK64, PCKT, PCK32);
  k_fill   <<<2064,  256, 0, stream>>>(loc, idxagg, aw, PCK64, PCKT, PCK32, LIST64, LISTT, LIST32, XMB);
  k_t2m    <<<8192,  256, 0, stream>>>(x, PCK64, LIST64, XMB);
  k_conv   <<<512,   256, 0, stream>>>(XMB, WT, convb, Y);
  k_xt     <<<4096,  256, 0, stream>>>(x, SWT, Y, LISTT, PCKT, NRM, XTB, BNP);
  k_bnfin  <<<1,     128, 0, stream>>>(BNP, gamma, beta, SS);
  k_conf   <<<8192,  256, 0, stream>>>(XTB, SS, confw, confb, O_CONF, WGT, XA);
  k_cluster<<<4096,  256, 0, stream>>>(XTB, SS, WGT, aw, PCK32, LIST32, O_XD, O_AWD, MAXB);
  k_awdnorm<<<1024,  256, 0, stream>>>(O_AWD, MAXB);
}